// Round 8
// baseline (666.054 us; speedup 1.0000x reference)
//
#include <hip/hip_runtime.h>

#define CNUM 1024
#define CDIM 256
#define EPS_CAND 6.0f

// out region offsets in FP32 elements (zbar, zsoft, zhard, symbols, phisoft)
#define OFF_ZBAR   ((size_t)0)
#define OFF_ZSOFT  ((size_t)16777216)
#define OFF_ZHARD  ((size_t)33554432)
#define OFF_SYM    ((size_t)50331648)
#define OFF_PHI    ((size_t)50397184)

typedef __attribute__((ext_vector_type(8))) short bf16x8;
typedef __attribute__((ext_vector_type(4))) float f32x4;
typedef __attribute__((ext_vector_type(4))) unsigned short u16x4;

__device__ __forceinline__ unsigned short f2bf(float f){
  unsigned u = __float_as_uint(f);
  u += 0x7fffu + ((u >> 16) & 1u);
  return (unsigned short)(u >> 16);
}
__device__ __forceinline__ float bf2f(unsigned short h){
  return __uint_as_float(((unsigned)h) << 16);
}
__device__ __forceinline__ float clamp01(float v){ return fminf(1.0f, fmaxf(0.0f, v)); }
__device__ __forceinline__ float dot4(float4 a, float4 b){ return a.x*b.x + a.y*b.y + a.z*b.z + a.w*b.w; }

// ---------- prep: centers fp32 -> bf16 row-major (cb16) + transposed (ct16) ----------
__global__ __launch_bounds__(256) void prep_convert(const float* __restrict__ centers,
                                                    unsigned short* __restrict__ cb16,
                                                    unsigned short* __restrict__ ct16){
  int gid = blockIdx.x*256 + threadIdx.x;        // 65536 = 1024 c x 64 quads
  int c = gid >> 6, d0 = (gid & 63)*4;
  float4 v = *reinterpret_cast<const float4*>(centers + (size_t)c*CDIM + d0);
  unsigned short b0=f2bf(v.x), b1=f2bf(v.y), b2=f2bf(v.z), b3=f2bf(v.w);
  unsigned lo = (unsigned)b0 | ((unsigned)b1<<16);
  unsigned hi = (unsigned)b2 | ((unsigned)b3<<16);
  *reinterpret_cast<uint2*>(cb16 + (size_t)c*CDIM + d0) = make_uint2(lo, hi);
  ct16[(size_t)(d0+0)*CNUM + c] = b0;
  ct16[(size_t)(d0+1)*CNUM + c] = b1;
  ct16[(size_t)(d0+2)*CNUM + c] = b2;
  ct16[(size_t)(d0+3)*CNUM + c] = b3;
}

__global__ __launch_bounds__(256) void prep_e2(const float* __restrict__ centers, float* __restrict__ e2){
  int k = blockIdx.x*256 + threadIdx.x;          // 1024
  const float4* c4 = reinterpret_cast<const float4*>(centers) + (size_t)k*(CDIM/4);
  float s = 0.f;
  #pragma unroll
  for (int i=0;i<CDIM/4;i++){ float4 v = c4[i]; s += dot4(v,v); }
  e2[k] = s;
}

// ---------- fused: GEMM1 + softmax/argmin(fp64-refine) + all outputs + GEMM2 ----------
// 32 tokens per block, 512 threads (8 waves), grid 2048.
__global__ __launch_bounds__(512, 4) void fused(const float* __restrict__ data,
                                                const float* __restrict__ centers,
                                                const unsigned short* __restrict__ cb16,
                                                const unsigned short* __restrict__ ct16,
                                                const float* __restrict__ e2g,
                                                float* __restrict__ out)
{
  __shared__ unsigned short sq[32*1024];   // 64 KB: sq bf16 -> phi bf16, rows 2048B, XOR swizzled
  __shared__ unsigned short zst[32*256];   // 16 KB: hard bf16 -> zsoft bf16, rows 512B, swizzled

  const int tid = threadIdx.x;
  const int w = tid>>6, lane = tid&63;
  const int l15 = lane&15, g = lane>>4;
  const int tok0 = blockIdx.x*32;
  const int bb = tok0>>10, hw0 = tok0&1023;

  // ---- P1: x-frags (regs, bf16) + x2 ----
  const int nt1 = w&1, mtb = w>>1;          // wave: token-half nt1, mt residue mtb
  const int myt = nt1*16 + l15;             // this lane's token (MFMA col)
  bf16x8 xf[8];
  float x2 = 0.f;
  {
    const float* xp = data + (size_t)bb*262144 + hw0 + myt;
    #pragma unroll
    for (int s=0;s<8;s++){
      bf16x8 v;
      #pragma unroll
      for (int u=0;u<8;u++){
        float f = xp[(size_t)(32*s+8*g+u)*1024];
        x2 += f*f;
        v[u] = (short)f2bf(f);
      }
      xf[s] = v;
    }
    x2 += __shfl_xor(x2, 16);
    x2 += __shfl_xor(x2, 32);
  }

  // ---- P2: GEMM1 -> sq bf16 in LDS (sq = x2 - 2 x.e + e2) ----
  for (int i=0;i<16;i+=2){
    int mt0 = mtb + 4*i, mt1 = mtb + 4*(i+1);
    f32x4 aA = {0.f,0.f,0.f,0.f}, aB = {0.f,0.f,0.f,0.f};
    const unsigned short* r0 = cb16 + (size_t)(16*mt0 + l15)*CDIM;
    const unsigned short* r1 = cb16 + (size_t)(16*mt1 + l15)*CDIM;
    #pragma unroll
    for (int s=0;s<8;s++){
      bf16x8 a0 = *reinterpret_cast<const bf16x8*>(r0 + 32*s + 8*g);
      bf16x8 a1 = *reinterpret_cast<const bf16x8*>(r1 + 32*s + 8*g);
      aA = __builtin_amdgcn_mfma_f32_16x16x32_bf16(a0, xf[s], aA, 0,0,0);
      aB = __builtin_amdgcn_mfma_f32_16x16x32_bf16(a1, xf[s], aB, 0,0,0);
    }
    {
      int c0 = 16*mt0 + 4*g;
      float4 e4 = *reinterpret_cast<const float4*>(e2g + c0);
      u16x4 pk;
      pk[0] = f2bf(x2 - 2.f*aA[0] + e4.x);
      pk[1] = f2bf(x2 - 2.f*aA[1] + e4.y);
      pk[2] = f2bf(x2 - 2.f*aA[2] + e4.z);
      pk[3] = f2bf(x2 - 2.f*aA[3] + e4.w);
      *reinterpret_cast<u16x4*>((char*)sq + (size_t)myt*2048 + ((2*c0) ^ ((myt&7)<<4))) = pk;
    }
    {
      int c0 = 16*mt1 + 4*g;
      float4 e4 = *reinterpret_cast<const float4*>(e2g + c0);
      u16x4 pk;
      pk[0] = f2bf(x2 - 2.f*aB[0] + e4.x);
      pk[1] = f2bf(x2 - 2.f*aB[1] + e4.y);
      pk[2] = f2bf(x2 - 2.f*aB[2] + e4.z);
      pk[3] = f2bf(x2 - 2.f*aB[3] + e4.w);
      *reinterpret_cast<u16x4*>((char*)sq + (size_t)myt*2048 + ((2*c0) ^ ((myt&7)<<4))) = pk;
    }
  }
  __syncthreads();

  // ---- P3/P4: per-token softmax + exact argmin + phi-bf16 + hard gather ----
  const int hbase = (lane>=32)?32:0;
  for (int p=0;p<2;p++){
    const int tg = tid>>5;                 // 0..15
    const int t  = p*16 + tg;
    const int j  = tid&31;
    const int tglob = tok0 + t;
    float a[32];
    float mns = 3.4e38f;
    #pragma unroll
    for (int i=0;i<32;i++){
      unsigned short h = *(const unsigned short*)((const char*)sq + (size_t)t*2048 + ((2*(j+32*i)) ^ ((t&7)<<4)));
      float sp = bf2f(h);
      a[i] = sp;
      mns = fminf(mns, sp);
    }
    #pragma unroll
    for (int m=16;m>=1;m>>=1) mns = fminf(mns, __shfl_xor(mns, m));
    float thr = mns + EPS_CAND;
    unsigned cm = 0;
    #pragma unroll
    for (int i=0;i<32;i++) if (a[i] < thr) cm |= (1u<<i);

    double bestd = 1.0e300; int bestk = CNUM;
    const float* xp = data + (size_t)bb*262144 + hw0 + t;
    for(;;){
      unsigned long long bal = __ballot(cm != 0);
      unsigned half = (lane<32)? (unsigned)(bal & 0xffffffffULL) : (unsigned)(bal>>32);
      if (!half) break;
      int src = __ffs(half)-1;
      unsigned cmsrc = (unsigned)__shfl((int)cm, hbase + src);
      int ii = __ffs(cmsrc)-1;
      int k = src + 32*ii;
      if (j==src) cm &= ~(1u<<ii);
      double acc = 0.0;
      const float* crow = centers + (size_t)k*CDIM;
      #pragma unroll
      for (int q=0;q<8;q++){
        double xv = (double)xp[(size_t)(j+32*q)*1024];
        double ev = (double)crow[j+32*q];
        double df = xv-ev; acc = fma(df,df,acc);
      }
      #pragma unroll
      for (int m=16;m>=1;m>>=1) acc += __shfl_xor(acc, m);
      if (acc < bestd || (acc==bestd && k<bestk)){ bestd=acc; bestk=k; }
    }
    if (j==0) out[OFF_SYM + tglob] = (float)bestk;

    float dmn = sqrtf(fmaxf(mns, 0.f));
    float sum = 0.f;
    #pragma unroll
    for (int i=0;i<32;i++){
      float d = sqrtf(fmaxf(a[i], 0.f));
      a[i] = __expf(dmn - d);
      sum += a[i];
    }
    #pragma unroll
    for (int m=16;m>=1;m>>=1) sum += __shfl_xor(sum, m);
    float rs = 1.f/sum;
    #pragma unroll
    for (int i=0;i<32;i++){
      unsigned short ph = f2bf(clamp01(a[i]*rs));
      *(unsigned short*)((char*)sq + (size_t)t*2048 + ((2*(j+32*i)) ^ ((t&7)<<4))) = ph;
    }
    // hard row -> zst (bf16, swizzled)
    const float* hrow = centers + (size_t)bestk*CDIM;
    #pragma unroll
    for (int q=0;q<8;q++){
      *(unsigned short*)((char*)zst + (size_t)t*512 + ((2*(j+32*q)) ^ ((t&7)<<4))) = f2bf(hrow[j+32*q]);
    }
  }
  __syncthreads();

  // ---- P5: coalesced stores — zbar/zhard from zst, phisoft from sq ----
  #pragma unroll
  for (int it=0; it<4; it++){
    int e = tid + 512*it;                  // 0..2047: d = e>>3, q = e&7
    int d = e>>3, q = e&7;
    float4 h; float* hp = (float*)&h;
    #pragma unroll
    for (int i2=0;i2<4;i2++){
      int t = 4*q + i2;
      hp[i2] = bf2f(*(const unsigned short*)((const char*)zst + (size_t)t*512 + ((2*d) ^ ((t&7)<<4))));
    }
    size_t base = (size_t)bb*262144 + (size_t)d*1024 + hw0 + 4*q;
    *reinterpret_cast<float4*>(out + OFF_ZBAR + base) = h;
    *reinterpret_cast<float4*>(out + OFF_ZHARD + base) = h;
  }
  #pragma unroll
  for (int it=0; it<16; it++){
    int e = tid + 512*it;                  // 0..8191: c = e>>3, q = e&7
    int c = e>>3, q = e&7;
    float4 v; float* vp = (float*)&v;
    #pragma unroll
    for (int i2=0;i2<4;i2++){
      int t = 4*q + i2;
      vp[i2] = bf2f(*(const unsigned short*)((const char*)sq + (size_t)t*2048 + ((2*c) ^ ((t&7)<<4))));
    }
    *reinterpret_cast<float4*>(out + OFF_PHI + (size_t)bb*1048576 + (size_t)c*1024 + hw0 + 4*q) = v;
  }
  __syncthreads();

  // ---- P6: GEMM2 — zsoft = phi @ centers (A = ct16 d-rows, B = phi from LDS) ----
  {
    f32x4 z00={0.f,0.f,0.f,0.f}, z01=z00, z10=z00, z11=z00;
    const unsigned short* ar0 = ct16 + (size_t)(16*w + l15)*CNUM;
    const unsigned short* ar1 = ct16 + (size_t)(16*(w+8) + l15)*CNUM;
    const int swzb = (l15&7)<<4;
    for (int s=0;s<32;s++){
      bf16x8 b0 = *reinterpret_cast<const bf16x8*>((const char*)sq + (size_t)l15*2048      + ((64*s+16*g) ^ swzb));
      bf16x8 b1 = *reinterpret_cast<const bf16x8*>((const char*)sq + (size_t)(16+l15)*2048 + ((64*s+16*g) ^ swzb));
      bf16x8 a0 = *reinterpret_cast<const bf16x8*>(ar0 + 32*s + 8*g);
      bf16x8 a1 = *reinterpret_cast<const bf16x8*>(ar1 + 32*s + 8*g);
      z00 = __builtin_amdgcn_mfma_f32_16x16x32_bf16(a0, b0, z00, 0,0,0);
      z01 = __builtin_amdgcn_mfma_f32_16x16x32_bf16(a0, b1, z01, 0,0,0);
      z10 = __builtin_amdgcn_mfma_f32_16x16x32_bf16(a1, b0, z10, 0,0,0);
      z11 = __builtin_amdgcn_mfma_f32_16x16x32_bf16(a1, b1, z11, 0,0,0);
    }
    // stage acc -> zst (bf16, swizzled): t = nt*16+l15, d = 16*mt+4g+r
    #pragma unroll
    for (int mi=0;mi<2;mi++){
      #pragma unroll
      for (int ntq=0;ntq<2;ntq++){
        f32x4 ac = (mi==0) ? (ntq==0 ? z00 : z01) : (ntq==0 ? z10 : z11);
        int mt = w + 8*mi;
        int t  = ntq*16 + l15;
        u16x4 pk;
        pk[0] = f2bf(ac[0]); pk[1] = f2bf(ac[1]);
        pk[2] = f2bf(ac[2]); pk[3] = f2bf(ac[3]);
        *reinterpret_cast<u16x4*>((char*)zst + (size_t)t*512 + ((32*mt+8*g) ^ ((t&7)<<4))) = pk;
      }
    }
  }
  __syncthreads();

  // ---- P7: zsoft store ----
  #pragma unroll
  for (int it=0; it<4; it++){
    int e = tid + 512*it;
    int d = e>>3, q = e&7;
    float4 h; float* hp = (float*)&h;
    #pragma unroll
    for (int i2=0;i2<4;i2++){
      int t = 4*q + i2;
      hp[i2] = bf2f(*(const unsigned short*)((const char*)zst + (size_t)t*512 + ((2*d) ^ ((t&7)<<4))));
    }
    *reinterpret_cast<float4*>(out + OFF_ZSOFT + (size_t)bb*262144 + (size_t)d*1024 + hw0 + 4*q) = h;
  }
}

extern "C" void kernel_launch(void* const* d_in, const int* in_sizes, int n_in,
                              void* d_out, int out_size, void* d_ws, size_t ws_size,
                              hipStream_t stream) {
  const float* data    = (const float*)d_in[0];
  const float* centers = (const float*)d_in[1];
  float* out           = (float*)d_out;

  unsigned short* cb16 = (unsigned short*)d_ws;                         // 512 KB
  unsigned short* ct16 = (unsigned short*)((char*)d_ws + 524288);       // 512 KB
  float*          e2   = (float*)((char*)d_ws + 1048576);               // 4 KB

  prep_convert<<<dim3(256), dim3(256), 0, stream>>>(centers, cb16, ct16);
  prep_e2<<<dim3(4), dim3(256), 0, stream>>>(centers, e2);
  fused<<<dim3(2048), dim3(512), 0, stream>>>(data, centers, cb16, ct16, e2, out);
}